// Round 6
// baseline (1453.408 us; speedup 1.0000x reference)
//
#include <hip/hip_runtime.h>
#include <math.h>

#define Lr    32
#define Hh    128
#define HP2   130
#define MROWS 160                  // rows padded: 4 waves x 5 chunks x 8 rows
#define STRIP 40                   // rows per wave
#define NCH   20                   // 8-row chunks per step
#define CHB   1024                 // chunk bytes = 8 rows x 128 k x 1 B fp8
#define WCELL (NCH * CHB)          // 20480 B weights per step
#define CELLB (WCELL + 2 * Hh * 4) // + b1 fp32 + Wf fp32 = 21504 B
#define NEPS  1e-8f

typedef float f32x2 __attribute__((ext_vector_type(2)));

#define AS1 __attribute__((address_space(1)))
#define AS3 __attribute__((address_space(3)))

// Async global->LDS DMA, HW-verified widths only: 16 B (m97) and 4 B (m03).
// Lane i's data lands at lds_base + i*size (m104/m108).
__device__ __forceinline__ void dma16(const void* g, void* l) {
    __builtin_amdgcn_global_load_lds((const AS1 unsigned int*)g, (AS3 unsigned int*)l, 16, 0, 0);
}
__device__ __forceinline__ void dma4(const void* g, void* l) {
    __builtin_amdgcn_global_load_lds((const AS1 unsigned int*)g, (AS3 unsigned int*)l, 4, 0, 0);
}

// Barrier draining LDS only — in-flight DMAs (vmcnt) survive across it.
__device__ __forceinline__ void bar_lds() {
    asm volatile("s_waitcnt lgkmcnt(0)\n\ts_barrier" ::: "memory");
}
#define WAITVM4 asm volatile("s_waitcnt vmcnt(4)" ::: "memory")
#define WAITVM3 asm volatile("s_waitcnt vmcnt(3)" ::: "memory")
#define WAITLG0 asm volatile("s_waitcnt lgkmcnt(0)" ::: "memory")

__device__ __forceinline__ int cell_of(int s) {
    const int i = s >> 5, jj = s & 31;
    return i * Lr + ((i & 1) ? (Lr - 1 - jj) : jj);
}

// Pack W1 into per-step blobs (visitation order): fp8-e4m3 weights in DMA
// layout (chunk = 8 rows x 128 k = 1024 B; lane l's 16 B = k{2l,2l+1} x 8 rows;
// dword d = rows 2d,2d+1: byte0=W[k0][r0] byte1=W[k0+1][r0] byte2=W[k0][r1]
// byte3=W[k0+1][r1]), then b1 fp32[128], Wf fp32[128].
__global__ __launch_bounds__(256)
void prep_blob(const float* __restrict__ W1, const float* __restrict__ b1,
               const float* __restrict__ Wf, unsigned char* __restrict__ blob) {
    const int s = blockIdx.x;
    const int cell = cell_of(s);
    const float* wsrc = W1 + (size_t)cell * (Hh * HP2);
    unsigned char* dst = blob + (size_t)s * CELLB;
    for (int idx = threadIdx.x; idx < NCH * 64; idx += 256) {
        const int ch = idx >> 6, l = idx & 63;
        const int k0 = 2 * l;
        unsigned int* o = (unsigned int*)(dst + ch * CHB + l * 16);
#pragma unroll
        for (int d = 0; d < 4; ++d) {
            const int r0 = ch * 8 + 2 * d, r1 = r0 + 1;
            const float a0 = (r0 < HP2) ? wsrc[k0 * HP2 + r0] : 0.f;
            const float c0 = (r0 < HP2) ? wsrc[(k0 + 1) * HP2 + r0] : 0.f;
            const float a1 = (r1 < HP2) ? wsrc[k0 * HP2 + r1] : 0.f;
            const float c1 = (r1 < HP2) ? wsrc[(k0 + 1) * HP2 + r1] : 0.f;
            int v = __builtin_amdgcn_cvt_pk_fp8_f32(a0, c0, 0, false);
            v = __builtin_amdgcn_cvt_pk_fp8_f32(a1, c1, v, true);
            o[d] = (unsigned int)v;
        }
    }
    float* bo = (float*)(dst + WCELL);
    for (int k = threadIdx.x; k < Hh; k += 256) {
        bo[k]      = b1[cell * Hh + k];
        bo[Hh + k] = Wf[cell * Hh + k];
    }
}

// 512 blocks x 1 batch element (2 blocks/CU). Wave w owns m-strip
// [40w, 40w+40): it DMAs its own 5 chunks (A=0-2, B=3-4) + its b1/Wf segments
// and is the sole consumer — per-wave vmcnt(N) waits; barriers stay lgkm-only
// so prefetch DMAs stay in flight across them.
__global__ __launch_bounds__(256, 2)
void rnn2d(const float* __restrict__ samples, const unsigned char* __restrict__ blob,
           const float* __restrict__ bfv, float* __restrict__ out)
{
    __shared__ __align__(16) unsigned char wreg[4 * 5 * CHB]; // 20 KB fp8 strips
    __shared__ float bw[4][2][2][64];   // [wave][parity][b1|wf][lane] 4 KB
    __shared__ float hv[Lr][Hh];        // 16 KB vertical hidden state
    __shared__ float inp2[MROWS];       // input vector; [130..159] stay 0
    __shared__ float prt[8][64];        // matvec partials
    __shared__ float smp[Lr * Lr];      // 4 KB staged samples
    __shared__ float bfs[Lr * Lr];      // 4 KB staged head bias
    __shared__ float fpart[2];          // head-dot wave partials (prev cell)

    const int t  = threadIdx.x;
    const int kp = t & 63;
    const int w  = t >> 6;
    const int u  = t & 127;
    const int b  = blockIdx.x;

    for (int idx = t; idx < Lr * Hh; idx += 256) ((float*)hv)[idx] = 0.f;
    for (int idx = t; idx < MROWS; idx += 256) inp2[idx] = (idx == 1) ? 2.f : 0.f;
    for (int idx = t; idx < Lr * Lr; idx += 256) {
        smp[idx] = samples[(size_t)b * (Lr * Lr) + idx];
        bfs[idx] = bfv[idx];
    }
    float lp = 0.f;
    __syncthreads();   // drains vmcnt too — DMA bookkeeping starts at 0

    unsigned char* lbase = wreg + w * (5 * CHB);

#define ISSUE_A(SN)                                                            \
    {                                                                          \
        const unsigned char* gs = blob + (size_t)(SN) * CELLB                  \
                                + (w * 5) * CHB + kp * 16;                     \
        dma16(gs,           lbase);                                            \
        dma16(gs + CHB,     lbase + CHB);                                      \
        dma16(gs + 2 * CHB, lbase + 2 * CHB);                                  \
    }
#define ISSUE_B(SN)                                                            \
    {                                                                          \
        const unsigned char* gs = blob + (size_t)(SN) * CELLB                  \
                                + (w * 5) * CHB + kp * 16;                     \
        dma16(gs + 3 * CHB, lbase + 3 * CHB);                                  \
        dma16(gs + 4 * CHB, lbase + 4 * CHB);                                  \
        const unsigned char* gb = blob + (size_t)(SN) * CELLB + WCELL          \
                                + (w & 1) * 256 + kp * 4;                      \
        dma4(gb,       &bw[w][(SN) & 1][0][0]);                                \
        dma4(gb + 512, &bw[w][(SN) & 1][1][0]);                                \
    }
#define CONSUME(C0, C1)                                                        \
    _Pragma("unroll")                                                          \
    for (int c_ = (C0); c_ < (C1); ++c_) {                                     \
        const uint4 dv = *(const uint4*)(lbase + c_ * CHB + kp * 16);          \
        const float2* ip = (const float2*)(inp2 + w * STRIP + c_ * 8);         \
        const float2 i0 = ip[0], i1 = ip[1], i2 = ip[2], i3 = ip[3];           \
        f32x2 f;                                                               \
        f = __builtin_amdgcn_cvt_pk_f32_fp8((int)dv.x, false);                 \
        a0 = fmaf(f.x, i0.x, a0); a1 = fmaf(f.y, i0.x, a1);                    \
        f = __builtin_amdgcn_cvt_pk_f32_fp8((int)dv.x, true);                  \
        a0 = fmaf(f.x, i0.y, a0); a1 = fmaf(f.y, i0.y, a1);                    \
        f = __builtin_amdgcn_cvt_pk_f32_fp8((int)dv.y, false);                 \
        a0 = fmaf(f.x, i1.x, a0); a1 = fmaf(f.y, i1.x, a1);                    \
        f = __builtin_amdgcn_cvt_pk_f32_fp8((int)dv.y, true);                  \
        a0 = fmaf(f.x, i1.y, a0); a1 = fmaf(f.y, i1.y, a1);                    \
        f = __builtin_amdgcn_cvt_pk_f32_fp8((int)dv.z, false);                 \
        a0 = fmaf(f.x, i2.x, a0); a1 = fmaf(f.y, i2.x, a1);                    \
        f = __builtin_amdgcn_cvt_pk_f32_fp8((int)dv.z, true);                  \
        a0 = fmaf(f.x, i2.y, a0); a1 = fmaf(f.y, i2.y, a1);                    \
        f = __builtin_amdgcn_cvt_pk_f32_fp8((int)dv.w, false);                 \
        a0 = fmaf(f.x, i3.x, a0); a1 = fmaf(f.y, i3.x, a1);                    \
        f = __builtin_amdgcn_cvt_pk_f32_fp8((int)dv.w, true);                  \
        a0 = fmaf(f.x, i3.y, a0); a1 = fmaf(f.y, i3.y, a1);                    \
    }
#define LPFIN(CC)                                                              \
    {                                                                          \
        const float z_    = fpart[0] + fpart[1] + bfs[CC];                     \
        const float xhat_ = 1.f / (1.f + expf(-z_));                           \
        const float mc_   = smp[CC];                                           \
        lp += logf(xhat_ + NEPS) * mc_ + logf(1.f - xhat_ + NEPS) * (1.f - mc_); \
    }

    ISSUE_A(0);   // 3 in flight
    ISSUE_B(0);   // 7 in flight — steady-state invariant at loop top
    for (int s = 0; s < Lr * Lr; ++s) {
        const int i_ = s >> 5, j_ = s & 31;
        const int c_col = (i_ & 1) ? (Lr - 1 - j_) : j_;
        const int sn = (s < Lr * Lr - 1) ? s + 1 : s;   // clamped prefetch

        WAITVM4;                       // drain A_s(3); B_s(4) stays in flight
        if (t == 128 && s > 0) { LPFIN(cell_of(s - 1)); }  // deferred lp tail
        float a0 = 0.f, a1 = 0.f;
        CONSUME(0, 3);
        WAITLG0; ISSUE_A(sn);          // refill A-slot -> 7 in flight
        WAITVM3;                       // drain B_s(4); A_{s+1}(3) stays
        CONSUME(3, 5);
        prt[w][kp] = a0; prt[4 + w][kp] = a1;
        WAITLG0; ISSUE_B(sn);          // -> 7 in flight across both barriers
        bar_lds();

        // epilogue: every wave rebuilds h for its u; state waves (0,1) update
        // hv + next-cell inp2, head waves (2,3) do the Wf-dot reduction.
        const int r_ = (u & 1) * 4, cl_ = u >> 1;
        const float s_ = prt[r_][cl_] + prt[r_ + 1][cl_]
                       + prt[r_ + 2][cl_] + prt[r_ + 3][cl_];
        const float h_ = tanhf(s_ + 2.f * bw[w][s & 1][0][kp]);
        if (w < 2) {
            hv[c_col][u] = h_;
            if (s + 1 < Lr * Lr) {
                const int sn_ = s + 1, in_ = sn_ >> 5, jn_ = sn_ & 31;
                const int cn_ = (in_ & 1) ? (Lr - 1 - jn_) : jn_;
                const float hvn_ = (cn_ == c_col) ? h_ : hv[cn_][u];
                inp2[u + 2] = ((jn_ == 0) ? 0.f : h_) + hvn_;
                if (u < 2) {
                    const float xh_ = (jn_ == 0) ? 0.f : smp[i_ * Lr + c_col];
                    const float xv_ = (in_ == 0) ? 0.f : smp[(in_ - 1) * Lr + cn_];
                    inp2[u] = (u == 0) ? (xh_ + xv_) : (2.f - xh_ - xv_);
                }
            }
        } else {
            float f_ = h_ * bw[w][s & 1][1][kp];
            f_ += __shfl_down(f_, 32);
            f_ += __shfl_down(f_, 16);
            f_ += __shfl_down(f_, 8);
            f_ += __shfl_down(f_, 4);
            f_ += __shfl_down(f_, 2);
            f_ += __shfl_down(f_, 1);
            if (kp == 0) fpart[w - 2] = f_;
        }
        bar_lds();
    }
    if (t == 128) {
        LPFIN(cell_of(Lr * Lr - 1));
        out[b] = lp;
    }
#undef ISSUE_A
#undef ISSUE_B
#undef CONSUME
#undef LPFIN
}

extern "C" void kernel_launch(void* const* d_in, const int* in_sizes, int n_in,
                              void* d_out, int out_size, void* d_ws, size_t ws_size,
                              hipStream_t stream) {
    const float* samples = (const float*)d_in[0];
    const float* W1      = (const float*)d_in[1];
    const float* b1      = (const float*)d_in[2];
    const float* Wf      = (const float*)d_in[3];
    const float* bf      = (const float*)d_in[4];
    float* outp = (float*)d_out;
    unsigned char* blob = (unsigned char*)d_ws;   // 1024 * 21504 = 22.0 MB

    prep_blob<<<1024, 256, 0, stream>>>(W1, b1, Wf, blob);
    rnn2d<<<512, 256, 0, stream>>>(samples, blob, bf, outp);
}